// Round 3
// baseline (2494.572 us; speedup 1.0000x reference)
//
#include <hip/hip_runtime.h>
#include <hip/hip_bf16.h>
#include <cstdint>

#define N_NODES 50000
#define IN_DIM  512
#define HID     256
#define NEDGE   600000
#define TOPO    4
#define DEGMAX  96

typedef __attribute__((ext_vector_type(4))) float floatx4;
typedef _Float16 half4 __attribute__((ext_vector_type(4)));
typedef _Float16 half8 __attribute__((ext_vector_type(8)));

// ---------------- f32 -> f16 converters (run once) -------------------------------
__global__ void conv_f2h_kernel(const float* __restrict__ src, _Float16* __restrict__ dst, int n4) {
  int i = blockIdx.x * 256 + threadIdx.x;
  if (i < n4) {
    float4 v = ((const float4*)src)[i];
    half4 h;
    h[0] = (_Float16)v.x; h[1] = (_Float16)v.y; h[2] = (_Float16)v.z; h[3] = (_Float16)v.w;
    ((half4*)dst)[i] = h;
  }
}

// ctx = [style | stress] -> fp16 [N][512]
__global__ void conv_ctx_kernel(const float* __restrict__ style, const float* __restrict__ stress,
                                _Float16* __restrict__ dst) {
  int i = blockIdx.x * 256 + threadIdx.x;
  if (i >= N_NODES * 128) return;
  int n = i >> 7, c4 = i & 127;
  int c = c4 * 4;
  const float* s = (c < 256) ? (style + (size_t)n * 256 + c) : (stress + (size_t)n * 256 + (c - 256));
  float4 v = *(const float4*)s;
  half4 h;
  h[0] = (_Float16)v.x; h[1] = (_Float16)v.y; h[2] = (_Float16)v.z; h[3] = (_Float16)v.w;
  ((half4*)(dst + (size_t)n * 512))[c4] = h;
}

// ---- all 17 weight matrices -> fp16, transposed to Wt[n][kd], one dispatch ------
// layout (fp16 elems): fW1t@0(131072) | gW0t@131072(4x131072) | gW1t@655360(4x65536)
//                      | gW2t@917504(4x65536) | aWt@1179648(4x65536); total 1441792
#define WT_FUS 0
#define WT_G0  131072
#define WT_G1  655360
#define WT_G2  917504
#define WT_AW  1179648
#define WT_TOT 1441792
__global__ void wconv_all_kernel(const float* __restrict__ fW1, const float* __restrict__ gW0,
                                 const float* __restrict__ gW1, const float* __restrict__ gW2,
                                 const float* __restrict__ aW, _Float16* __restrict__ wt) {
  int idx = blockIdx.x * 256 + threadIdx.x;
  if (idx >= WT_TOT) return;
  const float* src;
  int local, sh;
  if (idx < WT_G0) { src = fW1; sh = 9; local = idx; }
  else if (idx < WT_G1) { int r = idx - WT_G0; src = gW0 + (size_t)(r >> 17) * 131072; sh = 9; local = r & 131071; }
  else if (idx < WT_G2) { int r = idx - WT_G1; src = gW1 + (size_t)(r >> 16) * 65536; sh = 8; local = r & 65535; }
  else if (idx < WT_AW) { int r = idx - WT_G2; src = gW2 + (size_t)(r >> 16) * 65536; sh = 8; local = r & 65535; }
  else { int r = idx - WT_AW; src = aW + (size_t)(r >> 16) * 65536; sh = 8; local = r & 65535; }
  int n = local >> sh;
  int kd = local & ((1 << sh) - 1);
  wt[idx] = (_Float16)src[(size_t)kd * 256 + n];
}

// ---------------- GEMM: C[M,256] = A[M,KD] @ W[KD,256], fp16 MFMA, no LDS --------
// Block: 64 rows x 256 cols. Wave wv owns cols [wv*64, wv*64+64). 16 acc tiles.
// mode: 0 = store (+bias), 1 = tanh(x+bias). C fp16.
template <int KD>
__global__ __launch_bounds__(256) void gemm_f16_kernel(
    const _Float16* __restrict__ A, const _Float16* __restrict__ Wt,
    const float* __restrict__ bias, _Float16* __restrict__ C, int M, int mode) {
  const int tid = threadIdx.x;
  const int lane = tid & 63;
  const int wv = tid >> 6;
  const int mr = lane & 15;
  const int q = lane >> 4;
  const int r0 = blockIdx.x * 64;
  floatx4 acc[4][4];
#pragma unroll
  for (int g = 0; g < 4; ++g)
#pragma unroll
    for (int t = 0; t < 4; ++t) acc[g][t] = (floatx4){0.f, 0.f, 0.f, 0.f};

  const _Float16* pa[4];
#pragma unroll
  for (int g = 0; g < 4; ++g) {
    int r = r0 + g * 16 + mr;
    if (r > M - 1) r = M - 1;
    pa[g] = A + (size_t)r * KD + q * 8;
  }
  const _Float16* pb[4];
#pragma unroll
  for (int t = 0; t < 4; ++t) {
    int col = (wv * 4 + t) * 16 + mr;
    pb[t] = Wt + (size_t)col * KD + q * 8;
  }

#pragma unroll 2
  for (int it = 0; it < KD / 32; ++it) {
    half8 a[4], b[4];
#pragma unroll
    for (int g = 0; g < 4; ++g) { a[g] = *(const half8*)pa[g]; pa[g] += 32; }
#pragma unroll
    for (int t = 0; t < 4; ++t) { b[t] = *(const half8*)pb[t]; pb[t] += 32; }
#pragma unroll
    for (int g = 0; g < 4; ++g)
#pragma unroll
      for (int t = 0; t < 4; ++t)
        acc[g][t] = __builtin_amdgcn_mfma_f32_16x16x32_f16(a[g], b[t], acc[g][t], 0, 0, 0);
  }

  // D layout: col = lane&15 (= mr), row-in-tile = q*4 + reg
#pragma unroll
  for (int t = 0; t < 4; ++t) {
    int col = (wv * 4 + t) * 16 + mr;
    float bv = bias ? bias[col] : 0.f;
#pragma unroll
    for (int g = 0; g < 4; ++g) {
#pragma unroll
      for (int r4 = 0; r4 < 4; ++r4) {
        int row = r0 + g * 16 + q * 4 + r4;
        if (row < M) {
          float v = acc[g][t][r4] + bv;
          if (mode == 1) v = tanhf(v);
          C[(size_t)row * HID + col] = (_Float16)v;
        }
      }
    }
  }
}

// ---------------- CSR build (fixed-stride, no scan) ------------------------------
__global__ void zero_int_kernel(int* p, int n) {
  int i = blockIdx.x * 256 + threadIdx.x;
  if (i < n) p[i] = 0;
}
__global__ void fill_kernel(const int* __restrict__ src, const int* __restrict__ dst,
                            int* __restrict__ cur, int* __restrict__ csr_src, int n) {
  int i = blockIdx.x * 256 + threadIdx.x;
  if (i < n) {
    int d = dst[i];
    int slot = atomicAdd(&cur[d], 1);
    if (slot < DEGMAX) csr_src[(size_t)d * DEGMAX + slot] = src[i];
  }
}
__global__ void dinv_kernel(const int* __restrict__ deg, float* __restrict__ dinv, int n) {
  int i = blockIdx.x * 256 + threadIdx.x;
  if (i < n) dinv[i] = rsqrtf((float)(deg[i] + 1));
}

// ---------------- GCN aggregation (pull), bias+ReLU fused ------------------------
__global__ __launch_bounds__(256) void gcn_agg_kernel(
    const _Float16* __restrict__ hlin, const int* __restrict__ deg,
    const int* __restrict__ csr_src, const float* __restrict__ dinv,
    const float* __restrict__ bias, _Float16* __restrict__ out) {
  int w = (int)((blockIdx.x * blockDim.x + threadIdx.x) >> 6);
  int lane = threadIdx.x & 63;
  if (w >= N_NODES) return;
  float dv = dinv[w];
  half4 hv = ((const half4*)(hlin + (size_t)w * HID))[lane];
  float sn = dv * dv;
  float a0 = (float)hv[0] * sn, a1 = (float)hv[1] * sn,
        a2 = (float)hv[2] * sn, a3 = (float)hv[3] * sn;
  float c0 = 0.f, c1 = 0.f, c2 = 0.f, c3 = 0.f;
  int dg = deg[w];
  const int* sp = csr_src + (size_t)w * DEGMAX;
  int s = 0;
  for (; s + 2 <= dg; s += 2) {
    int sc0 = sp[s], sc1 = sp[s + 1];
    float nr0 = dinv[sc0] * dv, nr1 = dinv[sc1] * dv;
    half4 v0 = ((const half4*)(hlin + (size_t)sc0 * HID))[lane];
    half4 v1 = ((const half4*)(hlin + (size_t)sc1 * HID))[lane];
    a0 += (float)v0[0] * nr0; a1 += (float)v0[1] * nr0;
    a2 += (float)v0[2] * nr0; a3 += (float)v0[3] * nr0;
    c0 += (float)v1[0] * nr1; c1 += (float)v1[1] * nr1;
    c2 += (float)v1[2] * nr1; c3 += (float)v1[3] * nr1;
  }
  if (s < dg) {
    int sc = sp[s];
    float nr = dinv[sc] * dv;
    half4 v = ((const half4*)(hlin + (size_t)sc * HID))[lane];
    a0 += (float)v[0] * nr; a1 += (float)v[1] * nr;
    a2 += (float)v[2] * nr; a3 += (float)v[3] * nr;
  }
  float4 b = ((const float4*)bias)[lane];
  half4 r;
  r[0] = (_Float16)fmaxf(a0 + c0 + b.x, 0.f);
  r[1] = (_Float16)fmaxf(a1 + c1 + b.y, 0.f);
  r[2] = (_Float16)fmaxf(a2 + c2 + b.z, 0.f);
  r[3] = (_Float16)fmaxf(a3 + c3 + b.w, 0.f);
  ((half4*)(out + (size_t)w * HID))[lane] = r;
}

// ---------------- GAT: per-node attention coefficients ---------------------------
__global__ __launch_bounds__(256) void gat_prep_kernel(
    const _Float16* __restrict__ hlin, const float* __restrict__ a_src,
    const float* __restrict__ a_dst, float* __restrict__ asad) {
  int w = (int)((blockIdx.x * blockDim.x + threadIdx.x) >> 6);
  int lane = threadIdx.x & 63;
  if (w >= N_NODES) return;
  half4 h = ((const half4*)(hlin + (size_t)w * HID))[lane];
  float4 s4 = ((const float4*)a_src)[lane];
  float4 d4 = ((const float4*)a_dst)[lane];
  float hx = h[0], hy = h[1], hz = h[2], hw = h[3];
  float ps = hx * s4.x + hy * s4.y + hz * s4.z + hw * s4.w;
  float pd = hx * d4.x + hy * d4.y + hz * d4.z + hw * d4.w;
  for (int o = 1; o < 8; o <<= 1) { ps += __shfl_xor(ps, o, 64); pd += __shfl_xor(pd, o, 64); }
  if ((lane & 7) == 0) {
    int hh = lane >> 3;
    asad[(size_t)w * 16 + hh] = ps;
    asad[(size_t)w * 16 + 8 + hh] = pd;
  }
}

static __device__ __forceinline__ float lrelu(float e) {
  return e > 0.f ? e : 0.2f * e;
}

// ---------------- GAT aggregation: two-pass softmax per dst, pull -----------------
__global__ __launch_bounds__(256) void gat_agg_kernel(
    const _Float16* __restrict__ hlin, const int* __restrict__ deg,
    const int* __restrict__ csr_src, const float* __restrict__ asad,
    const float* __restrict__ bias, _Float16* __restrict__ out) {
  int w = (int)((blockIdx.x * blockDim.x + threadIdx.x) >> 6);
  int lane = threadIdx.x & 63;
  if (w >= N_NODES) return;
  int head = lane >> 3;
  float ad_d = asad[(size_t)w * 16 + 8 + head];
  float e_self = lrelu(asad[(size_t)w * 16 + head] + ad_d);
  int dg = deg[w];
  const int* sp = csr_src + (size_t)w * DEGMAX;
  float m = e_self;
  {
    int s = 0;
    for (; s + 2 <= dg; s += 2) {
      int sc0 = sp[s], sc1 = sp[s + 1];
      float e0 = lrelu(asad[(size_t)sc0 * 16 + head] + ad_d);
      float e1 = lrelu(asad[(size_t)sc1 * 16 + head] + ad_d);
      m = fmaxf(m, fmaxf(e0, e1));
    }
    if (s < dg) m = fmaxf(m, lrelu(asad[(size_t)sp[s] * 16 + head] + ad_d));
  }
  float l0 = __expf(e_self - m), l1 = 0.f;
  half4 hv = ((const half4*)(hlin + (size_t)w * HID))[lane];
  float a0 = (float)hv[0] * l0, a1 = (float)hv[1] * l0,
        a2 = (float)hv[2] * l0, a3 = (float)hv[3] * l0;
  float c0 = 0.f, c1 = 0.f, c2 = 0.f, c3 = 0.f;
  int s = 0;
  for (; s + 2 <= dg; s += 2) {
    int sc0 = sp[s], sc1 = sp[s + 1];
    float w0 = __expf(lrelu(asad[(size_t)sc0 * 16 + head] + ad_d) - m);
    float w1 = __expf(lrelu(asad[(size_t)sc1 * 16 + head] + ad_d) - m);
    half4 v0 = ((const half4*)(hlin + (size_t)sc0 * HID))[lane];
    half4 v1 = ((const half4*)(hlin + (size_t)sc1 * HID))[lane];
    l0 += w0; l1 += w1;
    a0 += (float)v0[0] * w0; a1 += (float)v0[1] * w0;
    a2 += (float)v0[2] * w0; a3 += (float)v0[3] * w0;
    c0 += (float)v1[0] * w1; c1 += (float)v1[1] * w1;
    c2 += (float)v1[2] * w1; c3 += (float)v1[3] * w1;
  }
  if (s < dg) {
    int sc = sp[s];
    float w0 = __expf(lrelu(asad[(size_t)sc * 16 + head] + ad_d) - m);
    half4 v = ((const half4*)(hlin + (size_t)sc * HID))[lane];
    l0 += w0;
    a0 += (float)v[0] * w0; a1 += (float)v[1] * w0;
    a2 += (float)v[2] * w0; a3 += (float)v[3] * w0;
  }
  float inv = 1.f / (l0 + l1);
  float4 b = ((const float4*)bias)[lane];
  half4 r;
  r[0] = (_Float16)((a0 + c0) * inv + b.x);
  r[1] = (_Float16)((a1 + c1) * inv + b.y);
  r[2] = (_Float16)((a2 + c2) * inv + b.z);
  r[3] = (_Float16)((a3 + c3) * inv + b.w);
  ((half4*)(out + (size_t)w * HID))[lane] = r;
}

// ---------------- fusion weights: logits = t @ W2 + b2, softmax(K=4) --------------
__global__ __launch_bounds__(256) void fusw_kernel(
    const _Float16* __restrict__ t, const float* __restrict__ W2,
    const float* __restrict__ b2, float* __restrict__ wout) {
  int w = (int)((blockIdx.x * blockDim.x + threadIdx.x) >> 6);
  int lane = threadIdx.x & 63;
  if (w >= N_NODES) return;
  half4 t4h = ((const half4*)(t + (size_t)w * HID))[lane];
  float tx = t4h[0], ty = t4h[1], tz = t4h[2], tw = t4h[3];
  int c = lane * 4;
  float4 w0 = ((const float4*)W2)[c + 0];
  float4 w1 = ((const float4*)W2)[c + 1];
  float4 w2 = ((const float4*)W2)[c + 2];
  float4 w3 = ((const float4*)W2)[c + 3];
  float p0 = tx * w0.x + ty * w1.x + tz * w2.x + tw * w3.x;
  float p1 = tx * w0.y + ty * w1.y + tz * w2.y + tw * w3.y;
  float p2 = tx * w0.z + ty * w1.z + tz * w2.z + tw * w3.z;
  float p3 = tx * w0.w + ty * w1.w + tz * w2.w + tw * w3.w;
  for (int o = 1; o < 64; o <<= 1) {
    p0 += __shfl_xor(p0, o, 64); p1 += __shfl_xor(p1, o, 64);
    p2 += __shfl_xor(p2, o, 64); p3 += __shfl_xor(p3, o, 64);
  }
  if (lane == 0) {
    p0 += b2[0]; p1 += b2[1]; p2 += b2[2]; p3 += b2[3];
    float mx = fmaxf(fmaxf(p0, p1), fmaxf(p2, p3));
    float e0 = __expf(p0 - mx), e1 = __expf(p1 - mx), e2 = __expf(p2 - mx), e3 = __expf(p3 - mx);
    float inv = 1.f / (e0 + e1 + e2 + e3);
    float4 r; r.x = e0 * inv; r.y = e1 * inv; r.z = e2 * inv; r.w = e3 * inv;
    ((float4*)wout)[w] = r;
  }
}

// ---------------- LayerNorm + weighted accumulate into d_out ----------------------
__global__ __launch_bounds__(256) void ln_acc_kernel(
    const _Float16* __restrict__ hin, const float* __restrict__ g,
    const float* __restrict__ b, const float* __restrict__ wsel, int kk,
    float* __restrict__ dout) {
  int w = (int)((blockIdx.x * blockDim.x + threadIdx.x) >> 6);
  int lane = threadIdx.x & 63;
  if (w >= N_NODES) return;
  half4 v4 = ((const half4*)(hin + (size_t)w * HID))[lane];
  float vx = v4[0], vy = v4[1], vz = v4[2], vw = v4[3];
  float s = vx + vy + vz + vw;
  for (int o = 1; o < 64; o <<= 1) s += __shfl_xor(s, o, 64);
  float mu = s * (1.f / HID);
  float dx = vx - mu, dy = vy - mu, dz = vz - mu, dw = vw - mu;
  float q = dx * dx + dy * dy + dz * dz + dw * dw;
  for (int o = 1; o < 64; o <<= 1) q += __shfl_xor(q, o, 64);
  float rs = rsqrtf(q * (1.f / HID) + 1e-5f);
  float4 g4 = ((const float4*)g)[lane];
  float4 b4 = ((const float4*)b)[lane];
  float wk = wsel[(size_t)w * 4 + kk];
  float4 r;
  r.x = (dx * rs * g4.x + b4.x) * wk;
  r.y = (dy * rs * g4.y + b4.y) * wk;
  r.z = (dz * rs * g4.z + b4.z) * wk;
  r.w = (dw * rs * g4.w + b4.w) * wk;
  float4* dp = (float4*)(dout + (size_t)w * HID) + lane;
  if (kk == 0) {
    *dp = r;
  } else {
    float4 old = *dp;
    old.x += r.x; old.y += r.y; old.z += r.z; old.w += r.w;
    *dp = old;
  }
}

extern "C" void kernel_launch(void* const* d_in, const int* in_sizes, int n_in,
                              void* d_out, int out_size, void* d_ws, size_t ws_size,
                              hipStream_t stream) {
  const float* x      = (const float*)d_in[0];
  const float* style  = (const float*)d_in[1];
  const float* stress = (const float*)d_in[2];
  const int* edges[4] = {(const int*)d_in[3], (const int*)d_in[4],
                         (const int*)d_in[5], (const int*)d_in[6]};
  const float* gW0 = (const float*)d_in[7];
  const float* gb0 = (const float*)d_in[8];
  const float* gW1 = (const float*)d_in[9];
  const float* gb1 = (const float*)d_in[10];
  const float* gW2 = (const float*)d_in[11];
  const float* gb2 = (const float*)d_in[12];
  const float* aW  = (const float*)d_in[13];
  const float* aas = (const float*)d_in[14];
  const float* aad = (const float*)d_in[15];
  const float* ab  = (const float*)d_in[16];
  const float* lg  = (const float*)d_in[17];
  const float* lb  = (const float*)d_in[18];
  const float* fW1 = (const float*)d_in[19];
  const float* fb1 = (const float*)d_in[20];
  const float* fW2 = (const float*)d_in[21];
  const float* fb2 = (const float*)d_in[22];
  float* out = (float*)d_out;
  (void)in_sizes; (void)n_in; (void)out_size; (void)ws_size;

  char* wsp = (char*)d_ws;
  size_t off = 0;
  auto alloc = [&](size_t bytes) -> void* {
    void* p = wsp + off;
    off += (bytes + 255) & ~(size_t)255;
    return p;
  };
  _Float16* h_act = (_Float16*)alloc((size_t)N_NODES * HID * 2);
  _Float16* h_lin = (_Float16*)alloc((size_t)N_NODES * HID * 2);
  _Float16* x_h   = (_Float16*)alloc((size_t)N_NODES * IN_DIM * 2);
  _Float16* wtall = (_Float16*)alloc((size_t)WT_TOT * 2);
  float* wsel = (float*)alloc((size_t)N_NODES * 4 * 4);
  float* dinv = (float*)alloc((size_t)N_NODES * 4);
  int* cur = (int*)alloc((size_t)N_NODES * 4);
  float* asad = (float*)alloc((size_t)N_NODES * 16 * 4);
  // ctx_h only lives until the fusion GEMM completes; csr_src starts after -> alias
  char* shared_region = (char*)alloc((size_t)N_NODES * IN_DIM * 2);  // 51.2 MB
  _Float16* ctx_h = (_Float16*)shared_region;
  int* csr_src = (int*)shared_region;  // N_NODES*DEGMAX*4 = 19.2 MB <= 51.2 MB

  dim3 blk(256);
  const int nodeWaveBlocks = N_NODES / 4;
  const int nBlocksN = (N_NODES + 255) / 256;
  const int nBlocksE = (NEDGE + 255) / 256;
  const int gemmBlocks = (N_NODES + 63) / 64;  // 782

  // ---- one-time conversions ----
  conv_f2h_kernel<<<(N_NODES * IN_DIM / 4 + 255) / 256, blk, 0, stream>>>(x, x_h, N_NODES * IN_DIM / 4);
  conv_ctx_kernel<<<(N_NODES * 128 + 255) / 256, blk, 0, stream>>>(style, stress, ctx_h);
  wconv_all_kernel<<<(WT_TOT + 255) / 256, blk, 0, stream>>>(fW1, gW0, gW1, gW2, aW, wtall);

  // ---- fusion gate ----
  gemm_f16_kernel<512><<<gemmBlocks, blk, 0, stream>>>(ctx_h, wtall + WT_FUS, fb1, h_lin, N_NODES, 1);
  fusw_kernel<<<nodeWaveBlocks, blk, 0, stream>>>(h_lin, fW2, fb2, wsel);

  for (int k = 0; k < TOPO; ++k) {
    const int* srcp = edges[k];
    const int* dstp = edges[k] + NEDGE;
    zero_int_kernel<<<nBlocksN, blk, 0, stream>>>(cur, N_NODES);
    fill_kernel<<<nBlocksE, blk, 0, stream>>>(srcp, dstp, cur, csr_src, NEDGE);
    dinv_kernel<<<nBlocksN, blk, 0, stream>>>(cur, dinv, N_NODES);

    // GCN0 (512 -> 256)
    gemm_f16_kernel<512><<<gemmBlocks, blk, 0, stream>>>(
        x_h, wtall + WT_G0 + (size_t)k * 131072, nullptr, h_lin, N_NODES, 0);
    gcn_agg_kernel<<<nodeWaveBlocks, blk, 0, stream>>>(h_lin, cur, csr_src, dinv,
                                                       gb0 + (size_t)k * HID, h_act);
    // GCN1
    gemm_f16_kernel<256><<<gemmBlocks, blk, 0, stream>>>(
        h_act, wtall + WT_G1 + (size_t)k * 65536, nullptr, h_lin, N_NODES, 0);
    gcn_agg_kernel<<<nodeWaveBlocks, blk, 0, stream>>>(h_lin, cur, csr_src, dinv,
                                                       gb1 + (size_t)k * HID, h_act);
    // GCN2
    gemm_f16_kernel<256><<<gemmBlocks, blk, 0, stream>>>(
        h_act, wtall + WT_G2 + (size_t)k * 65536, nullptr, h_lin, N_NODES, 0);
    gcn_agg_kernel<<<nodeWaveBlocks, blk, 0, stream>>>(h_lin, cur, csr_src, dinv,
                                                       gb2 + (size_t)k * HID, h_act);
    // GAT
    gemm_f16_kernel<256><<<gemmBlocks, blk, 0, stream>>>(
        h_act, wtall + WT_AW + (size_t)k * 65536, nullptr, h_lin, N_NODES, 0);
    gat_prep_kernel<<<nodeWaveBlocks, blk, 0, stream>>>(h_lin, aas + (size_t)k * HID,
                                                        aad + (size_t)k * HID, asad);
    gat_agg_kernel<<<nodeWaveBlocks, blk, 0, stream>>>(h_lin, cur, csr_src, asad,
                                                       ab + (size_t)k * HID, h_act);
    // LayerNorm + weighted accumulate
    ln_acc_kernel<<<nodeWaveBlocks, blk, 0, stream>>>(h_act, lg + (size_t)k * HID,
                                                      lb + (size_t)k * HID, wsel, k, out);
  }
}

// Round 4
// 1999.845 us; speedup vs baseline: 1.2474x; 1.2474x over previous
//
#include <hip/hip_runtime.h>
#include <hip/hip_bf16.h>
#include <cstdint>

#define N_NODES 50000
#define IN_DIM  512
#define HID     256
#define NEDGE   600000
#define TOPO    4
#define DEGMAX  96

typedef __attribute__((ext_vector_type(4))) float floatx4;
typedef _Float16 half4 __attribute__((ext_vector_type(4)));
typedef _Float16 half8 __attribute__((ext_vector_type(8)));

// ---------------- f32 -> f16 converters (run once) -------------------------------
__global__ void conv_f2h_kernel(const float* __restrict__ src, _Float16* __restrict__ dst, int n4) {
  int i = blockIdx.x * 256 + threadIdx.x;
  if (i < n4) {
    float4 v = ((const float4*)src)[i];
    half4 h;
    h[0] = (_Float16)v.x; h[1] = (_Float16)v.y; h[2] = (_Float16)v.z; h[3] = (_Float16)v.w;
    ((half4*)dst)[i] = h;
  }
}

// ctx = [style | stress] -> fp16 [N][512]
__global__ void conv_ctx_kernel(const float* __restrict__ style, const float* __restrict__ stress,
                                _Float16* __restrict__ dst) {
  int i = blockIdx.x * 256 + threadIdx.x;
  if (i >= N_NODES * 128) return;
  int n = i >> 7, c4 = i & 127;
  int c = c4 * 4;
  const float* s = (c < 256) ? (style + (size_t)n * 256 + c) : (stress + (size_t)n * 256 + (c - 256));
  float4 v = *(const float4*)s;
  half4 h;
  h[0] = (_Float16)v.x; h[1] = (_Float16)v.y; h[2] = (_Float16)v.z; h[3] = (_Float16)v.w;
  ((half4*)(dst + (size_t)n * 512))[c4] = h;
}

// ---- all 17 weight matrices -> fp16, transposed to Wt[n][kd], one dispatch ------
#define WT_FUS 0
#define WT_G0  131072
#define WT_G1  655360
#define WT_G2  917504
#define WT_AW  1179648
#define WT_TOT 1441792
__global__ void wconv_all_kernel(const float* __restrict__ fW1, const float* __restrict__ gW0,
                                 const float* __restrict__ gW1, const float* __restrict__ gW2,
                                 const float* __restrict__ aW, _Float16* __restrict__ wt) {
  int idx = blockIdx.x * 256 + threadIdx.x;
  if (idx >= WT_TOT) return;
  const float* src;
  int local, sh;
  if (idx < WT_G0) { src = fW1; sh = 9; local = idx; }
  else if (idx < WT_G1) { int r = idx - WT_G0; src = gW0 + (size_t)(r >> 17) * 131072; sh = 9; local = r & 131071; }
  else if (idx < WT_G2) { int r = idx - WT_G1; src = gW1 + (size_t)(r >> 16) * 65536; sh = 8; local = r & 65535; }
  else if (idx < WT_AW) { int r = idx - WT_G2; src = gW2 + (size_t)(r >> 16) * 65536; sh = 8; local = r & 65535; }
  else { int r = idx - WT_AW; src = aW + (size_t)(r >> 16) * 65536; sh = 8; local = r & 65535; }
  int n = local >> sh;
  int kd = local & ((1 << sh) - 1);
  wt[idx] = (_Float16)src[(size_t)kd * 256 + n];
}

// ---------------- GEMM: C[M,256] = A[M,KD] @ W[KD,256], fp16 MFMA ----------------
// Tile 64 rows x 256 cols per block (256 threads, 4 waves; wave wv owns cols
// [wv*64, wv*64+64)). A staged in LDS in fragment order (conflict-free b128 both
// ways); B frags direct global->reg with 1-iter prefetch; LDS double-buffered,
// one barrier per K-iter. MFMA operands swapped so each lane's D covers 4
// consecutive columns -> half4 stores. mode: 0 = store(+bias), 1 = tanh(x+bias).
template <int KD>
__global__ __launch_bounds__(256, 3) void gemm_f16_kernel(
    const _Float16* __restrict__ A, const _Float16* __restrict__ Wt,
    const float* __restrict__ bias, _Float16* __restrict__ C, int M, int mode) {
  constexpr int NIT = KD / 32;
  __shared__ __align__(16) _Float16 As[2][2048];  // 4 frags x 64 lanes x 8 halves
  const int tid = threadIdx.x;
  const int lane = tid & 63;
  const int wv = tid >> 6;
  const int mr = lane & 15;
  const int q = (lane >> 4) & 3;
  const int r0 = blockIdx.x * 64;

  // A staging: thread t owns frag-slot t: g=t>>6, mr_s=t&15, q_s=(t>>4)&3
  {
  }
  int arow = r0 + ((tid >> 6) * 16) + (tid & 15);
  if (arow > M - 1) arow = M - 1;
  const _Float16* pa = A + (size_t)arow * KD + ((tid >> 4) & 3) * 8;
  const _Float16* pb[4];
#pragma unroll
  for (int t = 0; t < 4; ++t)
    pb[t] = Wt + (size_t)((wv * 4 + t) * 16 + mr) * KD + q * 8;

  floatx4 acc[4][4];
#pragma unroll
  for (int g = 0; g < 4; ++g)
#pragma unroll
    for (int t = 0; t < 4; ++t) acc[g][t] = (floatx4){0.f, 0.f, 0.f, 0.f};

  half8 a0, a1, b0[4], b1[4];
  a0 = *(const half8*)pa; pa += 32;
#pragma unroll
  for (int t = 0; t < 4; ++t) { b0[t] = *(const half8*)pb[t]; pb[t] += 32; }
  *(half8*)&As[0][(unsigned)tid * 8] = a0;
  if (NIT > 1) { a1 = *(const half8*)pa; pa += 32; }
  __syncthreads();

#pragma unroll 1
  for (int it = 0; it < NIT; it += 2) {
    // ---- even half: compute from As[0] with b0 ----
    if (it + 1 < NIT) {
      *(half8*)&As[1][(unsigned)tid * 8] = a1;
#pragma unroll
      for (int t = 0; t < 4; ++t) { b1[t] = *(const half8*)pb[t]; pb[t] += 32; }
      if (it + 2 < NIT) { a0 = *(const half8*)pa; pa += 32; }
    }
    {
      half8 af[4];
#pragma unroll
      for (int g = 0; g < 4; ++g) af[g] = *(const half8*)&As[0][(g * 64 + lane) * 8];
#pragma unroll
      for (int g = 0; g < 4; ++g)
#pragma unroll
        for (int t = 0; t < 4; ++t)
          acc[g][t] = __builtin_amdgcn_mfma_f32_16x16x32_f16(b0[t], af[g], acc[g][t], 0, 0, 0);
    }
    if (it + 1 < NIT) {
      __syncthreads();
      // ---- odd half: compute from As[1] with b1 ----
      if (it + 2 < NIT) {
        *(half8*)&As[0][(unsigned)tid * 8] = a0;
#pragma unroll
        for (int t = 0; t < 4; ++t) { b0[t] = *(const half8*)pb[t]; pb[t] += 32; }
        if (it + 3 < NIT) { a1 = *(const half8*)pa; pa += 32; }
      }
      half8 af[4];
#pragma unroll
      for (int g = 0; g < 4; ++g) af[g] = *(const half8*)&As[1][(g * 64 + lane) * 8];
#pragma unroll
      for (int g = 0; g < 4; ++g)
#pragma unroll
        for (int t = 0; t < 4; ++t)
          acc[g][t] = __builtin_amdgcn_mfma_f32_16x16x32_f16(b1[t], af[g], acc[g][t], 0, 0, 0);
      if (it + 2 < NIT) __syncthreads();
    }
  }

  // Epilogue: D (swapped operands) -> lane holds rows r0+g*16+mr, cols c0..c0+3
#pragma unroll
  for (int t = 0; t < 4; ++t) {
    int c0 = (wv * 4 + t) * 16 + q * 4;
    float4 bv;
    if (bias) bv = *(const float4*)&bias[c0];
    else { bv.x = 0.f; bv.y = 0.f; bv.z = 0.f; bv.w = 0.f; }
#pragma unroll
    for (int g = 0; g < 4; ++g) {
      int row = r0 + g * 16 + mr;
      if (row < M) {
        half4 o;
#pragma unroll
        for (int r = 0; r < 4; ++r) {
          float v = acc[g][t][r] + (&bv.x)[r];
          if (mode == 1) v = tanhf(v);
          o[r] = (_Float16)v;
        }
        *(half4*)&C[(size_t)row * HID + c0] = o;
      }
    }
  }
}

// ---------------- CSR build (fixed-stride, no scan) ------------------------------
__global__ void zero_int_kernel(int* p, int n) {
  int i = blockIdx.x * 256 + threadIdx.x;
  if (i < n) p[i] = 0;
}
__global__ void fill_kernel(const int* __restrict__ src, const int* __restrict__ dst,
                            int* __restrict__ cur, int* __restrict__ csr_src, int n) {
  int i = blockIdx.x * 256 + threadIdx.x;
  if (i < n) {
    int d = dst[i];
    int slot = atomicAdd(&cur[d], 1);
    if (slot < DEGMAX) csr_src[(size_t)d * DEGMAX + slot] = src[i];
  }
}
__global__ void dinv_kernel(const int* __restrict__ deg, float* __restrict__ dinv, int n) {
  int i = blockIdx.x * 256 + threadIdx.x;
  if (i < n) dinv[i] = rsqrtf((float)(deg[i] + 1));
}

// ---------------- GCN aggregation (pull), bias+ReLU fused, 4-wide MLP ------------
__global__ __launch_bounds__(256) void gcn_agg_kernel(
    const _Float16* __restrict__ hlin, const int* __restrict__ deg,
    const int* __restrict__ csr_src, const float* __restrict__ dinv,
    const float* __restrict__ bias, _Float16* __restrict__ out) {
  int w = (int)((blockIdx.x * blockDim.x + threadIdx.x) >> 6);
  int lane = threadIdx.x & 63;
  if (w >= N_NODES) return;
  float dv = dinv[w];
  half4 hv = ((const half4*)(hlin + (size_t)w * HID))[lane];
  float sn = dv * dv;
  float A0 = (float)hv[0] * sn, A1 = (float)hv[1] * sn,
        A2 = (float)hv[2] * sn, A3 = (float)hv[3] * sn;
  float B0 = 0.f, B1 = 0.f, B2 = 0.f, B3 = 0.f;
  float C0 = 0.f, C1 = 0.f, C2 = 0.f, C3 = 0.f;
  float D0 = 0.f, D1 = 0.f, D2 = 0.f, D3 = 0.f;
  int dg = deg[w];
  const int* sp = csr_src + (size_t)w * DEGMAX;
  int s = 0;
  for (; s + 4 <= dg; s += 4) {
    int i0 = sp[s], i1 = sp[s + 1], i2 = sp[s + 2], i3 = sp[s + 3];
    float n0 = dinv[i0] * dv, n1 = dinv[i1] * dv, n2 = dinv[i2] * dv, n3 = dinv[i3] * dv;
    half4 v0 = ((const half4*)(hlin + (size_t)i0 * HID))[lane];
    half4 v1 = ((const half4*)(hlin + (size_t)i1 * HID))[lane];
    half4 v2 = ((const half4*)(hlin + (size_t)i2 * HID))[lane];
    half4 v3 = ((const half4*)(hlin + (size_t)i3 * HID))[lane];
    A0 += (float)v0[0] * n0; A1 += (float)v0[1] * n0; A2 += (float)v0[2] * n0; A3 += (float)v0[3] * n0;
    B0 += (float)v1[0] * n1; B1 += (float)v1[1] * n1; B2 += (float)v1[2] * n1; B3 += (float)v1[3] * n1;
    C0 += (float)v2[0] * n2; C1 += (float)v2[1] * n2; C2 += (float)v2[2] * n2; C3 += (float)v2[3] * n2;
    D0 += (float)v3[0] * n3; D1 += (float)v3[1] * n3; D2 += (float)v3[2] * n3; D3 += (float)v3[3] * n3;
  }
  for (; s < dg; ++s) {
    int sc = sp[s];
    float nr = dinv[sc] * dv;
    half4 v = ((const half4*)(hlin + (size_t)sc * HID))[lane];
    A0 += (float)v[0] * nr; A1 += (float)v[1] * nr;
    A2 += (float)v[2] * nr; A3 += (float)v[3] * nr;
  }
  float4 b = ((const float4*)bias)[lane];
  half4 r;
  r[0] = (_Float16)fmaxf(A0 + B0 + C0 + D0 + b.x, 0.f);
  r[1] = (_Float16)fmaxf(A1 + B1 + C1 + D1 + b.y, 0.f);
  r[2] = (_Float16)fmaxf(A2 + B2 + C2 + D2 + b.z, 0.f);
  r[3] = (_Float16)fmaxf(A3 + B3 + C3 + D3 + b.w, 0.f);
  ((half4*)(out + (size_t)w * HID))[lane] = r;
}

// ---------------- GAT: per-node attention coefficients ---------------------------
__global__ __launch_bounds__(256) void gat_prep_kernel(
    const _Float16* __restrict__ hlin, const float* __restrict__ a_src,
    const float* __restrict__ a_dst, float* __restrict__ asad) {
  int w = (int)((blockIdx.x * blockDim.x + threadIdx.x) >> 6);
  int lane = threadIdx.x & 63;
  if (w >= N_NODES) return;
  half4 h = ((const half4*)(hlin + (size_t)w * HID))[lane];
  float4 s4 = ((const float4*)a_src)[lane];
  float4 d4 = ((const float4*)a_dst)[lane];
  float hx = h[0], hy = h[1], hz = h[2], hw = h[3];
  float ps = hx * s4.x + hy * s4.y + hz * s4.z + hw * s4.w;
  float pd = hx * d4.x + hy * d4.y + hz * d4.z + hw * d4.w;
  for (int o = 1; o < 8; o <<= 1) { ps += __shfl_xor(ps, o, 64); pd += __shfl_xor(pd, o, 64); }
  if ((lane & 7) == 0) {
    int hh = lane >> 3;
    asad[(size_t)w * 16 + hh] = ps;
    asad[(size_t)w * 16 + 8 + hh] = pd;
  }
}

static __device__ __forceinline__ float lrelu(float e) {
  return e > 0.f ? e : 0.2f * e;
}

// ---------------- GAT aggregation: two-pass softmax per dst, 4-wide MLP -----------
__global__ __launch_bounds__(256) void gat_agg_kernel(
    const _Float16* __restrict__ hlin, const int* __restrict__ deg,
    const int* __restrict__ csr_src, const float* __restrict__ asad,
    const float* __restrict__ bias, _Float16* __restrict__ out) {
  int w = (int)((blockIdx.x * blockDim.x + threadIdx.x) >> 6);
  int lane = threadIdx.x & 63;
  if (w >= N_NODES) return;
  int head = lane >> 3;
  float ad_d = asad[(size_t)w * 16 + 8 + head];
  float e_self = lrelu(asad[(size_t)w * 16 + head] + ad_d);
  int dg = deg[w];
  const int* sp = csr_src + (size_t)w * DEGMAX;
  // pass 1: max logit
  float m = e_self;
  {
    int s = 0;
    for (; s + 4 <= dg; s += 4) {
      float e0 = lrelu(asad[(size_t)sp[s] * 16 + head] + ad_d);
      float e1 = lrelu(asad[(size_t)sp[s + 1] * 16 + head] + ad_d);
      float e2 = lrelu(asad[(size_t)sp[s + 2] * 16 + head] + ad_d);
      float e3 = lrelu(asad[(size_t)sp[s + 3] * 16 + head] + ad_d);
      m = fmaxf(m, fmaxf(fmaxf(e0, e1), fmaxf(e2, e3)));
    }
    for (; s < dg; ++s) m = fmaxf(m, lrelu(asad[(size_t)sp[s] * 16 + head] + ad_d));
  }
  // pass 2: accumulate
  float lA = __expf(e_self - m), lB = 0.f, lC = 0.f, lD = 0.f;
  half4 hv = ((const half4*)(hlin + (size_t)w * HID))[lane];
  float A0 = (float)hv[0] * lA, A1 = (float)hv[1] * lA,
        A2 = (float)hv[2] * lA, A3 = (float)hv[3] * lA;
  float B0 = 0.f, B1 = 0.f, B2 = 0.f, B3 = 0.f;
  float C0 = 0.f, C1 = 0.f, C2 = 0.f, C3 = 0.f;
  float D0 = 0.f, D1 = 0.f, D2 = 0.f, D3 = 0.f;
  int s = 0;
  for (; s + 4 <= dg; s += 4) {
    int i0 = sp[s], i1 = sp[s + 1], i2 = sp[s + 2], i3 = sp[s + 3];
    float w0 = __expf(lrelu(asad[(size_t)i0 * 16 + head] + ad_d) - m);
    float w1 = __expf(lrelu(asad[(size_t)i1 * 16 + head] + ad_d) - m);
    float w2 = __expf(lrelu(asad[(size_t)i2 * 16 + head] + ad_d) - m);
    float w3 = __expf(lrelu(asad[(size_t)i3 * 16 + head] + ad_d) - m);
    half4 v0 = ((const half4*)(hlin + (size_t)i0 * HID))[lane];
    half4 v1 = ((const half4*)(hlin + (size_t)i1 * HID))[lane];
    half4 v2 = ((const half4*)(hlin + (size_t)i2 * HID))[lane];
    half4 v3 = ((const half4*)(hlin + (size_t)i3 * HID))[lane];
    lA += w0; lB += w1; lC += w2; lD += w3;
    A0 += (float)v0[0] * w0; A1 += (float)v0[1] * w0; A2 += (float)v0[2] * w0; A3 += (float)v0[3] * w0;
    B0 += (float)v1[0] * w1; B1 += (float)v1[1] * w1; B2 += (float)v1[2] * w1; B3 += (float)v1[3] * w1;
    C0 += (float)v2[0] * w2; C1 += (float)v2[1] * w2; C2 += (float)v2[2] * w2; C3 += (float)v2[3] * w2;
    D0 += (float)v3[0] * w3; D1 += (float)v3[1] * w3; D2 += (float)v3[2] * w3; D3 += (float)v3[3] * w3;
  }
  for (; s < dg; ++s) {
    int sc = sp[s];
    float w0 = __expf(lrelu(asad[(size_t)sc * 16 + head] + ad_d) - m);
    half4 v = ((const half4*)(hlin + (size_t)sc * HID))[lane];
    lA += w0;
    A0 += (float)v[0] * w0; A1 += (float)v[1] * w0;
    A2 += (float)v[2] * w0; A3 += (float)v[3] * w0;
  }
  float inv = 1.f / (lA + lB + lC + lD);
  float4 b = ((const float4*)bias)[lane];
  half4 r;
  r[0] = (_Float16)((A0 + B0 + C0 + D0) * inv + b.x);
  r[1] = (_Float16)((A1 + B1 + C1 + D1) * inv + b.y);
  r[2] = (_Float16)((A2 + B2 + C2 + D2) * inv + b.z);
  r[3] = (_Float16)((A3 + B3 + C3 + D3) * inv + b.w);
  ((half4*)(out + (size_t)w * HID))[lane] = r;
}

// ---------------- fusion weights: logits = t @ W2 + b2, softmax(K=4) --------------
__global__ __launch_bounds__(256) void fusw_kernel(
    const _Float16* __restrict__ t, const float* __restrict__ W2,
    const float* __restrict__ b2, float* __restrict__ wout) {
  int w = (int)((blockIdx.x * blockDim.x + threadIdx.x) >> 6);
  int lane = threadIdx.x & 63;
  if (w >= N_NODES) return;
  half4 t4h = ((const half4*)(t + (size_t)w * HID))[lane];
  float tx = t4h[0], ty = t4h[1], tz = t4h[2], tw = t4h[3];
  int c = lane * 4;
  float4 w0 = ((const float4*)W2)[c + 0];
  float4 w1 = ((const float4*)W2)[c + 1];
  float4 w2 = ((const float4*)W2)[c + 2];
  float4 w3 = ((const float4*)W2)[c + 3];
  float p0 = tx * w0.x + ty * w1.x + tz * w2.x + tw * w3.x;
  float p1 = tx * w0.y + ty * w1.y + tz * w2.y + tw * w3.y;
  float p2 = tx * w0.z + ty * w1.z + tz * w2.z + tw * w3.z;
  float p3 = tx * w0.w + ty * w1.w + tz * w2.w + tw * w3.w;
  for (int o = 1; o < 64; o <<= 1) {
    p0 += __shfl_xor(p0, o, 64); p1 += __shfl_xor(p1, o, 64);
    p2 += __shfl_xor(p2, o, 64); p3 += __shfl_xor(p3, o, 64);
  }
  if (lane == 0) {
    p0 += b2[0]; p1 += b2[1]; p2 += b2[2]; p3 += b2[3];
    float mx = fmaxf(fmaxf(p0, p1), fmaxf(p2, p3));
    float e0 = __expf(p0 - mx), e1 = __expf(p1 - mx), e2 = __expf(p2 - mx), e3 = __expf(p3 - mx);
    float inv = 1.f / (e0 + e1 + e2 + e3);
    float4 r; r.x = e0 * inv; r.y = e1 * inv; r.z = e2 * inv; r.w = e3 * inv;
    ((float4*)wout)[w] = r;
  }
}

// ---------------- LayerNorm + weighted accumulate into d_out ----------------------
__global__ __launch_bounds__(256) void ln_acc_kernel(
    const _Float16* __restrict__ hin, const float* __restrict__ g,
    const float* __restrict__ b, const float* __restrict__ wsel, int kk,
    float* __restrict__ dout) {
  int w = (int)((blockIdx.x * blockDim.x + threadIdx.x) >> 6);
  int lane = threadIdx.x & 63;
  if (w >= N_NODES) return;
  half4 v4 = ((const half4*)(hin + (size_t)w * HID))[lane];
  float vx = v4[0], vy = v4[1], vz = v4[2], vw = v4[3];
  float s = vx + vy + vz + vw;
  for (int o = 1; o < 64; o <<= 1) s += __shfl_xor(s, o, 64);
  float mu = s * (1.f / HID);
  float dx = vx - mu, dy = vy - mu, dz = vz - mu, dw = vw - mu;
  float q = dx * dx + dy * dy + dz * dz + dw * dw;
  for (int o = 1; o < 64; o <<= 1) q += __shfl_xor(q, o, 64);
  float rs = rsqrtf(q * (1.f / HID) + 1e-5f);
  float4 g4 = ((const float4*)g)[lane];
  float4 b4 = ((const float4*)b)[lane];
  float wk = wsel[(size_t)w * 4 + kk];
  float4 r;
  r.x = (dx * rs * g4.x + b4.x) * wk;
  r.y = (dy * rs * g4.y + b4.y) * wk;
  r.z = (dz * rs * g4.z + b4.z) * wk;
  r.w = (dw * rs * g4.w + b4.w) * wk;
  float4* dp = (float4*)(dout + (size_t)w * HID) + lane;
  if (kk == 0) {
    *dp = r;
  } else {
    float4 old = *dp;
    old.x += r.x; old.y += r.y; old.z += r.z; old.w += r.w;
    *dp = old;
  }
}

extern "C" void kernel_launch(void* const* d_in, const int* in_sizes, int n_in,
                              void* d_out, int out_size, void* d_ws, size_t ws_size,
                              hipStream_t stream) {
  const float* x      = (const float*)d_in[0];
  const float* style  = (const float*)d_in[1];
  const float* stress = (const float*)d_in[2];
  const int* edges[4] = {(const int*)d_in[3], (const int*)d_in[4],
                         (const int*)d_in[5], (const int*)d_in[6]};
  const float* gW0 = (const float*)d_in[7];
  const float* gb0 = (const float*)d_in[8];
  const float* gW1 = (const float*)d_in[9];
  const float* gb1 = (const float*)d_in[10];
  const float* gW2 = (const float*)d_in[11];
  const float* gb2 = (const float*)d_in[12];
  const float* aW  = (const float*)d_in[13];
  const float* aas = (const float*)d_in[14];
  const float* aad = (const float*)d_in[15];
  const float* ab  = (const float*)d_in[16];
  const float* lg  = (const float*)d_in[17];
  const float* lb  = (const float*)d_in[18];
  const float* fW1 = (const float*)d_in[19];
  const float* fb1 = (const float*)d_in[20];
  const float* fW2 = (const float*)d_in[21];
  const float* fb2 = (const float*)d_in[22];
  float* out = (float*)d_out;
  (void)in_sizes; (void)n_in; (void)out_size; (void)ws_size;

  char* wsp = (char*)d_ws;
  size_t off = 0;
  auto alloc = [&](size_t bytes) -> void* {
    void* p = wsp + off;
    off += (bytes + 255) & ~(size_t)255;
    return p;
  };
  _Float16* h_act = (_Float16*)alloc((size_t)N_NODES * HID * 2);
  _Float16* h_lin = (_Float16*)alloc((size_t)N_NODES * HID * 2);
  _Float16* x_h   = (_Float16*)alloc((size_t)N_NODES * IN_DIM * 2);
  _Float16* wtall = (_Float16*)alloc((size_t)WT_TOT * 2);
  float* wsel = (float*)alloc((size_t)N_NODES * 4 * 4);
  float* dinv = (float*)alloc((size_t)N_NODES * 4);
  int* cur = (int*)alloc((size_t)N_NODES * 4);
  float* asad = (float*)alloc((size_t)N_NODES * 16 * 4);
  // ctx_h only lives until the fusion GEMM completes; csr_src aliases it after
  char* shared_region = (char*)alloc((size_t)N_NODES * IN_DIM * 2);  // 51.2 MB
  _Float16* ctx_h = (_Float16*)shared_region;
  int* csr_src = (int*)shared_region;  // 19.2 MB <= 51.2 MB

  dim3 blk(256);
  const int nodeWaveBlocks = N_NODES / 4;
  const int nBlocksN = (N_NODES + 255) / 256;
  const int nBlocksE = (NEDGE + 255) / 256;
  const int gemmBlocks = (N_NODES + 63) / 64;  // 782

  // ---- one-time conversions ----
  conv_f2h_kernel<<<(N_NODES * IN_DIM / 4 + 255) / 256, blk, 0, stream>>>(x, x_h, N_NODES * IN_DIM / 4);
  conv_ctx_kernel<<<(N_NODES * 128 + 255) / 256, blk, 0, stream>>>(style, stress, ctx_h);
  wconv_all_kernel<<<(WT_TOT + 255) / 256, blk, 0, stream>>>(fW1, gW0, gW1, gW2, aW, wtall);

  // ---- fusion gate ----
  gemm_f16_kernel<512><<<gemmBlocks, blk, 0, stream>>>(ctx_h, wtall + WT_FUS, fb1, h_lin, N_NODES, 1);
  fusw_kernel<<<nodeWaveBlocks, blk, 0, stream>>>(h_lin, fW2, fb2, wsel);

  for (int k = 0; k < TOPO; ++k) {
    const int* srcp = edges[k];
    const int* dstp = edges[k] + NEDGE;
    zero_int_kernel<<<nBlocksN, blk, 0, stream>>>(cur, N_NODES);
    fill_kernel<<<nBlocksE, blk, 0, stream>>>(srcp, dstp, cur, csr_src, NEDGE);
    dinv_kernel<<<nBlocksN, blk, 0, stream>>>(cur, dinv, N_NODES);

    // GCN0 (512 -> 256)
    gemm_f16_kernel<512><<<gemmBlocks, blk, 0, stream>>>(
        x_h, wtall + WT_G0 + (size_t)k * 131072, nullptr, h_lin, N_NODES, 0);
    gcn_agg_kernel<<<nodeWaveBlocks, blk, 0, stream>>>(h_lin, cur, csr_src, dinv,
                                                       gb0 + (size_t)k * HID, h_act);
    // GCN1
    gemm_f16_kernel<256><<<gemmBlocks, blk, 0, stream>>>(
        h_act, wtall + WT_G1 + (size_t)k * 65536, nullptr, h_lin, N_NODES, 0);
    gcn_agg_kernel<<<nodeWaveBlocks, blk, 0, stream>>>(h_lin, cur, csr_src, dinv,
                                                       gb1 + (size_t)k * HID, h_act);
    // GCN2
    gemm_f16_kernel<256><<<gemmBlocks, blk, 0, stream>>>(
        h_act, wtall + WT_G2 + (size_t)k * 65536, nullptr, h_lin, N_NODES, 0);
    gcn_agg_kernel<<<nodeWaveBlocks, blk, 0, stream>>>(h_lin, cur, csr_src, dinv,
                                                       gb2 + (size_t)k * HID, h_act);
    // GAT
    gemm_f16_kernel<256><<<gemmBlocks, blk, 0, stream>>>(
        h_act, wtall + WT_AW + (size_t)k * 65536, nullptr, h_lin, N_NODES, 0);
    gat_prep_kernel<<<nodeWaveBlocks, blk, 0, stream>>>(h_lin, aas + (size_t)k * HID,
                                                        aad + (size_t)k * HID, asad);
    gat_agg_kernel<<<nodeWaveBlocks, blk, 0, stream>>>(h_lin, cur, csr_src, asad,
                                                       ab + (size_t)k * HID, h_act);
    // LayerNorm + weighted accumulate
    ln_acc_kernel<<<nodeWaveBlocks, blk, 0, stream>>>(h_act, lg + (size_t)k * HID,
                                                      lb + (size_t)k * HID, wsel, k, out);
  }
}